// Round 16
// baseline (37.646 us; speedup 1.0000x reference)
//
#include <hip/hip_runtime.h>
#include <hip/hip_bf16.h>
#include <math.h>

// DDRFMixer: out[b,t,d] = sum_n softmax_n(x[b,t,:]·W[n,:]) * x[b,t-off_n,d]
// x: [B,T,D] fp32, W: [7,D] fp32, out: [B,T,D] fp32
// B=4, T=4096, D=1024, offsets = {1,2,4,8,16,32,64}
//
// R15 = R8 (best: 34.4 us) + FORCED all-upfront loads:
//  - R9 tried issuing all 32 VMEM loads (4 xv + 28 taps) before the
//    dot/reduce/softmax chain; rocprof proved the compiler SANK them back
//    (VGPR stayed 32). This round pins them with
//    __builtin_amdgcn_sched_barrier(0) after the load block — a hard
//    scheduler fence. All 32 loads go out in one burst (deep per-wave MLP);
//    s_waitcnt drains progressively (k=0 compute tolerates 21 outstanding).
//  - Verification signal: VGPR_Count >= 140 proves the hoist held.
//  - Occupancy drop to ~3 waves/SIMD is acceptable: R8/R13/R14 proved
//    occupancy (33-56%) does not correlate with dur; per-wave MLP is the
//    untested axis.
// Kept verbatim from R8: 512-thr blocks, 8 rows/block, one wave per row,
// W in LDS, DPP wave reduce, clamp+mask causality, no-max softmax,
// XCD-bijective swizzle, plain float4 stores.

#define N_TAPS 7
#define DIM 1024
#define T_LEN 4096
#define BLOCK_THREADS 512
#define ROWS_PER_BLOCK 8     // one wave per row, 8 waves per block

// ---- DPP helpers: canonical GCN wave64 sum ----
template <int CTRL>
__device__ __forceinline__ float dpp_mov0(float v) {
    return __builtin_bit_cast(float,
        __builtin_amdgcn_update_dpp(0, __builtin_bit_cast(int, v),
                                    CTRL, 0xf, 0xf, true));
}
__device__ __forceinline__ float wave_sum_bcast(float v) {
    v += dpp_mov0<0x111>(v);   // row_shr:1
    v += dpp_mov0<0x112>(v);   // row_shr:2
    v += dpp_mov0<0x114>(v);   // row_shr:4
    v += dpp_mov0<0x118>(v);   // row_shr:8
    v += dpp_mov0<0x142>(v);   // row_bcast:15
    v += dpp_mov0<0x143>(v);   // row_bcast:31 -> lane63 = total
    return __builtin_bit_cast(float,
        __builtin_amdgcn_readlane(__builtin_bit_cast(int, v), 63));
}

__global__ __launch_bounds__(BLOCK_THREADS) void ddrf_mixer_kernel(
    const float* __restrict__ x,   // [B*T, D]
    const float* __restrict__ W,   // [N_TAPS, D]
    float* __restrict__ out,       // [B*T, D]
    int n_rows)
{
    constexpr int offs[N_TAPS] = {1, 2, 4, 8, 16, 32, 64};

    __shared__ float wlds[N_TAPS * DIM];   // 28 KB

    // ---- stage W into LDS (once per block) ----
    for (int i = threadIdx.x; i < N_TAPS * (DIM / 4); i += BLOCK_THREADS) {
        reinterpret_cast<float4*>(wlds)[i] =
            reinterpret_cast<const float4*>(W)[i];
    }
    __syncthreads();

    // ---- bijective XCD swizzle (gridDim.x = 2048, % 8 == 0) ----
    const int per = gridDim.x >> 3;
    const int wg  = (blockIdx.x & 7) * per + (blockIdx.x >> 3);

    const int wave = threadIdx.x >> 6;
    const int lane = threadIdx.x & 63;
    const int dofs = lane * 4;               // lane's base within each 256-chunk

    const int row = wg * ROWS_PER_BLOCK + wave;   // one wave per row
    if (row >= n_rows) return;
    const int t = row & (T_LEN - 1);
    const float* xrow = x + (size_t)row * DIM;

    // ---- causal clamp + mask (branch-free) ----
    const float* trow[N_TAPS];
    float tmask[N_TAPS];
#pragma unroll
    for (int n = 0; n < N_TAPS; ++n) {
        const bool ok = (t >= offs[n]);
        trow[n]  = xrow - (size_t)(ok ? offs[n] : 0) * DIM;
        tmask[n] = ok ? 1.0f : 0.0f;
    }

    // ======== ALL 32 VMEM loads in one burst (xv, then taps by k) ========
    float4 xv[4];
#pragma unroll
    for (int k = 0; k < 4; ++k)
        xv[k] = *reinterpret_cast<const float4*>(xrow + k * 256 + dofs);

    float4 tap[4][N_TAPS];                   // [k][n]
#pragma unroll
    for (int k = 0; k < 4; ++k)
#pragma unroll
        for (int n = 0; n < N_TAPS; ++n)
            tap[k][n] = *reinterpret_cast<const float4*>(
                trow[n] + k * 256 + dofs);

    // Hard scheduler fence: nothing crosses. Loads stay hoisted (R9's
    // failure mode was the compiler sinking these to their uses).
    __builtin_amdgcn_sched_barrier(0);

    // ---- Phase 1: partial dots vs W (LDS pipe; overlaps tap latency) ----
    float p[N_TAPS];
#pragma unroll
    for (int n = 0; n < N_TAPS; ++n) {
        const float* wrow = &wlds[n * DIM];
        float4 w0 = *reinterpret_cast<const float4*>(wrow + 0 * 256 + dofs);
        float4 w1 = *reinterpret_cast<const float4*>(wrow + 1 * 256 + dofs);
        float4 w2 = *reinterpret_cast<const float4*>(wrow + 2 * 256 + dofs);
        float4 w3 = *reinterpret_cast<const float4*>(wrow + 3 * 256 + dofs);
        float s0 = fmaf(xv[0].x, w0.x, fmaf(xv[0].y, w0.y, fmaf(xv[0].z, w0.z, xv[0].w * w0.w)));
        float s1 = fmaf(xv[1].x, w1.x, fmaf(xv[1].y, w1.y, fmaf(xv[1].z, w1.z, xv[1].w * w1.w)));
        float s2 = fmaf(xv[2].x, w2.x, fmaf(xv[2].y, w2.y, fmaf(xv[2].z, w2.z, xv[2].w * w2.w)));
        float s3 = fmaf(xv[3].x, w3.x, fmaf(xv[3].y, w3.y, fmaf(xv[3].z, w3.z, xv[3].w * w3.w)));
        p[n] = (s0 + s1) + (s2 + s3);
    }

    // ---- DPP wave reduce (VALU pipe; 7 independent chains) ----
#pragma unroll
    for (int n = 0; n < N_TAPS; ++n)
        p[n] = wave_sum_bcast(p[n]);

    // ---- softmax over 7 taps (no max subtraction; logits small) + mask ----
    float wn[N_TAPS];
    float wsum = 0.f;
#pragma unroll
    for (int n = 0; n < N_TAPS; ++n) {
        wn[n] = __expf(p[n]);
        wsum += wn[n];
    }
    const float inv = 1.0f / wsum;
    float weff[N_TAPS];
#pragma unroll
    for (int n = 0; n < N_TAPS; ++n) weff[n] = wn[n] * inv * tmask[n];

    // ---- Phase 2: combine (taps already in registers / in flight) ----
    float* orow = out + (size_t)row * DIM;
#pragma unroll
    for (int k = 0; k < 4; ++k) {
        float4 a = make_float4(0.f, 0.f, 0.f, 0.f);
#pragma unroll
        for (int n = 0; n < N_TAPS; ++n) {
            a.x = fmaf(weff[n], tap[k][n].x, a.x);
            a.y = fmaf(weff[n], tap[k][n].y, a.y);
            a.z = fmaf(weff[n], tap[k][n].z, a.z);
            a.w = fmaf(weff[n], tap[k][n].w, a.w);
        }
        *reinterpret_cast<float4*>(orow + k * 256 + dofs) = a;
    }
}

extern "C" void kernel_launch(void* const* d_in, const int* in_sizes, int n_in,
                              void* d_out, int out_size, void* d_ws, size_t ws_size,
                              hipStream_t stream) {
    const float* x = (const float*)d_in[0];   // [B,T,D] fp32
    const float* W = (const float*)d_in[1];   // [N_TAPS,D] fp32
    float* out = (float*)d_out;               // [B,T,D] fp32

    const int n_rows   = in_sizes[0] / DIM;          // B*T = 16384
    const int n_blocks = n_rows / ROWS_PER_BLOCK;    // 2048 (divisible by 8)

    ddrf_mixer_kernel<<<n_blocks, BLOCK_THREADS, 0, stream>>>(x, W, out, n_rows);
}

// Round 17
// 34.470 us; speedup vs baseline: 1.0921x; 1.0921x over previous
//
#include <hip/hip_runtime.h>
#include <hip/hip_bf16.h>
#include <math.h>

// DDRFMixer: out[b,t,d] = sum_n softmax_n(x[b,t,:]·W[n,:]) * x[b,t-off_n,d]
// x: [B,T,D] fp32, W: [7,D] fp32, out: [B,T,D] fp32
// B=4, T=4096, D=1024, offsets = {1,2,4,8,16,32,64}
//
// R16 = R8 VERBATIM (session best: 34.4 us). Seven structural probes
// (R9-R15: per-wave MLP x3, TLP x2, two-pass, LDS-tile) all regressed or
// were neutral; occupancy 18-56% showed no correlation with dur. The
// binding constraint is ~36 KB/row of tap traffic that structurally cannot
// hit L1 (per-CU tap window ~256 KB >> 32 KB L1; the 64-row tap halo
// equals the 64-rows-per-CU work quota, so no tiling reduces L2 traffic
// without starving the grid), served at L2/L3 latency through a chain with
// a serial softmax dependency. R8's configuration is the measured optimum.
//
// Structure: one wave per row, 8 rows per 512-thr block, W staged in LDS,
// tap k=0 prefetch before the DPP reduce (clamp+mask causality), no-max
// softmax, 1-ahead k-pipeline in combine, XCD-bijective swizzle.

#define N_TAPS 7
#define DIM 1024
#define T_LEN 4096
#define BLOCK_THREADS 512
#define ROWS_PER_BLOCK 8

// ---- DPP helpers: canonical GCN wave64 sum ----
template <int CTRL>
__device__ __forceinline__ float dpp_mov0(float v) {
    return __builtin_bit_cast(float,
        __builtin_amdgcn_update_dpp(0, __builtin_bit_cast(int, v),
                                    CTRL, 0xf, 0xf, true));
}
__device__ __forceinline__ float wave_sum_bcast(float v) {
    v += dpp_mov0<0x111>(v);   // row_shr:1
    v += dpp_mov0<0x112>(v);   // row_shr:2
    v += dpp_mov0<0x114>(v);   // row_shr:4
    v += dpp_mov0<0x118>(v);   // row_shr:8   -> lane15 of each row16 = row sum
    v += dpp_mov0<0x142>(v);   // row_bcast:15 -> lane31/63 = half sums
    v += dpp_mov0<0x143>(v);   // row_bcast:31 -> lane63 = total
    return __builtin_bit_cast(float,
        __builtin_amdgcn_readlane(__builtin_bit_cast(int, v), 63));
}

__global__ __launch_bounds__(BLOCK_THREADS) void ddrf_mixer_kernel(
    const float* __restrict__ x,   // [B*T, D]
    const float* __restrict__ W,   // [N_TAPS, D]
    float* __restrict__ out,       // [B*T, D]
    int n_rows)
{
    constexpr int offs[N_TAPS] = {1, 2, 4, 8, 16, 32, 64};

    __shared__ float wlds[N_TAPS * DIM];   // 28 KB

    // ---- stage W into LDS (once per block) ----
    for (int i = threadIdx.x; i < N_TAPS * (DIM / 4); i += BLOCK_THREADS) {
        reinterpret_cast<float4*>(wlds)[i] =
            reinterpret_cast<const float4*>(W)[i];
    }
    __syncthreads();

    // ---- bijective XCD swizzle (gridDim.x = 2048, % 8 == 0) ----
    const int per = gridDim.x >> 3;
    const int wg  = (blockIdx.x & 7) * per + (blockIdx.x >> 3);

    const int wave = threadIdx.x >> 6;
    const int lane = threadIdx.x & 63;
    const int dofs = lane * 4;               // lane's base within each 256-chunk

    const int row = wg * ROWS_PER_BLOCK + wave;   // one wave per row
    if (row >= n_rows) return;
    const int t = row & (T_LEN - 1);
    const float* xrow = x + (size_t)row * DIM;

    // ---- this row's 16 elements (issue first; dots wait on these) ----
    float4 xv[4];
#pragma unroll
    for (int k = 0; k < 4; ++k)
        xv[k] = *reinterpret_cast<const float4*>(xrow + k * 256 + dofs);

    // ---- causal clamp + mask (branch-free => tap loads can issue now) ----
    const float* trow[N_TAPS];
    float tmask[N_TAPS];
#pragma unroll
    for (int n = 0; n < N_TAPS; ++n) {
        const bool ok = (t >= offs[n]);
        trow[n]  = xrow - (size_t)(ok ? offs[n] : 0) * DIM;
        tmask[n] = ok ? 1.0f : 0.0f;
    }

    // ---- prefetch k=0 taps: in flight across the reduce+softmax chain ----
    float4 tap[N_TAPS];
#pragma unroll
    for (int n = 0; n < N_TAPS; ++n)
        tap[n] = *reinterpret_cast<const float4*>(trow[n] + dofs);

    // ---- Phase 1: partial dots vs W (from LDS, parallel pipe) ----
    float p[N_TAPS];
#pragma unroll
    for (int n = 0; n < N_TAPS; ++n) {
        const float* wrow = &wlds[n * DIM];
        float4 w0 = *reinterpret_cast<const float4*>(wrow + 0 * 256 + dofs);
        float4 w1 = *reinterpret_cast<const float4*>(wrow + 1 * 256 + dofs);
        float4 w2 = *reinterpret_cast<const float4*>(wrow + 2 * 256 + dofs);
        float4 w3 = *reinterpret_cast<const float4*>(wrow + 3 * 256 + dofs);
        float s0 = fmaf(xv[0].x, w0.x, fmaf(xv[0].y, w0.y, fmaf(xv[0].z, w0.z, xv[0].w * w0.w)));
        float s1 = fmaf(xv[1].x, w1.x, fmaf(xv[1].y, w1.y, fmaf(xv[1].z, w1.z, xv[1].w * w1.w)));
        float s2 = fmaf(xv[2].x, w2.x, fmaf(xv[2].y, w2.y, fmaf(xv[2].z, w2.z, xv[2].w * w2.w)));
        float s3 = fmaf(xv[3].x, w3.x, fmaf(xv[3].y, w3.y, fmaf(xv[3].z, w3.z, xv[3].w * w3.w)));
        p[n] = (s0 + s1) + (s2 + s3);
    }

    // ---- DPP wave reduce (VALU pipe; 7 independent chains) ----
#pragma unroll
    for (int n = 0; n < N_TAPS; ++n)
        p[n] = wave_sum_bcast(p[n]);

    // ---- softmax over 7 taps, no max subtraction (|logit| small, exp-safe)
    //      + causal mask ----
    float wn[N_TAPS];
    float wsum = 0.f;
#pragma unroll
    for (int n = 0; n < N_TAPS; ++n) {
        wn[n] = __expf(p[n]);
        wsum += wn[n];
    }
    const float inv = 1.0f / wsum;
    float weff[N_TAPS];
#pragma unroll
    for (int n = 0; n < N_TAPS; ++n) weff[n] = wn[n] * inv * tmask[n];

    // ---- Phase 2: combine, 1-chunk-ahead pipeline over k ----
    float* orow = out + (size_t)row * DIM;
#pragma unroll
    for (int k = 0; k < 4; ++k) {
        float4 nxt[N_TAPS];
        if (k < 3) {
#pragma unroll
            for (int n = 0; n < N_TAPS; ++n)
                nxt[n] = *reinterpret_cast<const float4*>(
                    trow[n] + (k + 1) * 256 + dofs);
        }
        float4 a = make_float4(0.f, 0.f, 0.f, 0.f);
#pragma unroll
        for (int n = 0; n < N_TAPS; ++n) {
            a.x = fmaf(weff[n], tap[n].x, a.x);
            a.y = fmaf(weff[n], tap[n].y, a.y);
            a.z = fmaf(weff[n], tap[n].z, a.z);
            a.w = fmaf(weff[n], tap[n].w, a.w);
        }
        *reinterpret_cast<float4*>(orow + k * 256 + dofs) = a;
        if (k < 3) {
#pragma unroll
            for (int n = 0; n < N_TAPS; ++n) tap[n] = nxt[n];
        }
    }
}

extern "C" void kernel_launch(void* const* d_in, const int* in_sizes, int n_in,
                              void* d_out, int out_size, void* d_ws, size_t ws_size,
                              hipStream_t stream) {
    const float* x = (const float*)d_in[0];   // [B,T,D] fp32
    const float* W = (const float*)d_in[1];   // [N_TAPS,D] fp32
    float* out = (float*)d_out;               // [B,T,D] fp32

    const int n_rows   = in_sizes[0] / DIM;          // B*T = 16384
    const int n_blocks = n_rows / ROWS_PER_BLOCK;    // 2048 (divisible by 8)

    ddrf_mixer_kernel<<<n_blocks, BLOCK_THREADS, 0, stream>>>(x, W, out, n_rows);
}